// Round 5
// baseline (499.285 us; speedup 1.0000x reference)
//
#include <hip/hip_runtime.h>
#include <hip/hip_bf16.h>
#include <stdint.h>

#define NB 8
#define CH 256
#define DQ 128
#define NE 256
#define NN 4096

using bf16x8 = __attribute__((ext_vector_type(8))) __bf16;
using bf16x4 = __attribute__((ext_vector_type(4))) __bf16;
using f32x4  = __attribute__((ext_vector_type(4))) float;

__device__ __forceinline__ void gl_lds16(const void* g, void* l){
  __builtin_amdgcn_global_load_lds(
      (const __attribute__((address_space(1))) unsigned int*)g,
      (__attribute__((address_space(3))) unsigned int*)l, 16, 0, 0);
}

// -------------------------------------------------------- weight prep -------
__global__ __launch_bounds__(256) void wprep_k(
    const float* __restrict__ Wq, const float* __restrict__ Wk,
    const float* __restrict__ Wv, const float* __restrict__ Wo,
    __bf16* __restrict__ Wb)
{
  const int bidx = blockIdx.x;
  const float* s4;  __bf16* d;  int i = bidx * 256 + threadIdx.x;
  if (bidx < 32)       { s4 = Wq; d = Wb;          }
  else if (bidx < 64)  { s4 = Wk; d = Wb + 32768;  i -= 32 * 256; }
  else if (bidx < 128) { s4 = Wv; d = Wb + 65536;  i -= 64 * 256; }
  else                 { s4 = Wo; d = Wb + 131072; i -= 128 * 256; }
  float4 v = ((const float4*)s4)[i];
  bf16x4 o; o[0]=(__bf16)v.x; o[1]=(__bf16)v.y; o[2]=(__bf16)v.z; o[3]=(__bf16)v.w;
  *(bf16x4*)(d + i * 4) = o;
}

// ------------------------------------------------- x/y transpose + cvt ------
// [b][c][n] fp32  ->  [b][n][c] bf16   (coalesced loads, 16B stores)
__global__ __launch_bounds__(256) void xyprep_k(
    const float* __restrict__ x, const float* __restrict__ y,
    __bf16* __restrict__ xt, __bf16* __restrict__ yt)
{
  const int b = blockIdx.y;
  const float* src = blockIdx.z ? y : x;
  __bf16* dst      = blockIdx.z ? yt : xt;
  const int n    = blockIdx.x * 64 + (threadIdx.x & 63);
  const int cgrp = threadIdx.x >> 6;
  const float* sb = src + (size_t)b * CH * NN + n;
  __bf16* db = dst + ((size_t)b * NN + n) * CH;
#pragma unroll
  for (int cc = 0; cc < 8; ++cc) {
    const int c0 = cgrp * 64 + cc * 8;
    bf16x8 o;
#pragma unroll
    for (int s = 0; s < 8; ++s) o[s] = (__bf16)sb[(size_t)(c0 + s) * NN];
    *(bf16x8*)(db + c0) = o;
  }
}

// ---------------------------------------------------------------- proj Q ----
__global__ __launch_bounds__(256) void proj_q_k(
    const __bf16* __restrict__ yt, const __bf16* __restrict__ Wqb,
    const float* __restrict__ bq, __bf16* __restrict__ Q)
{
  const int b    = blockIdx.y;
  const int w    = threadIdx.x >> 6;
  const int lane = threadIdx.x & 63;
  const int cq   = lane & 15, g = lane >> 4;
  const int n0   = blockIdx.x * 64 + w * 16;
  const float scale = 0.08838834764831845f;  // 1/sqrt(128)

  f32x4 acc[8] = {};
  const __bf16* yb = yt + ((size_t)b * NN + n0 + cq) * CH;
#pragma unroll
  for (int kc = 0; kc < 8; ++kc) {
    const int kb = kc * 32 + g * 8;
    bf16x8 af = *(const bf16x8*)(yb + kb);
#pragma unroll
    for (int ct = 0; ct < 8; ++ct) {
      bf16x8 bfr = *(const bf16x8*)(Wqb + (ct * 16 + cq) * CH + kb);
      acc[ct] = __builtin_amdgcn_mfma_f32_16x16x32_bf16(af, bfr, acc[ct], 0, 0, 0);
    }
  }
#pragma unroll
  for (int ct = 0; ct < 8; ++ct) {
    const int col = ct * 16 + cq;
    const float bias = bq[col];
#pragma unroll
    for (int r = 0; r < 4; ++r) {
      const int n = n0 + g * 4 + r;
      Q[((size_t)b * NN + n) * DQ + col] = (__bf16)((acc[ct][r] + bias) * scale);
    }
  }
}

// --------------------------------------------------------------- proj KV ----
// K[n][d] normal orientation; V via swapped operands -> writes Vt[e][n] direct.
__global__ __launch_bounds__(256) void proj_kv_k(
    const __bf16* __restrict__ xt,
    const __bf16* __restrict__ Wkb, const float* __restrict__ bk,
    const __bf16* __restrict__ Wvb, const float* __restrict__ bv,
    __bf16* __restrict__ K, __bf16* __restrict__ Vt)
{
  const int b    = blockIdx.y;
  const int w    = threadIdx.x >> 6;
  const int lane = threadIdx.x & 63;
  const int cq   = lane & 15, g = lane >> 4;
  const int n0   = blockIdx.x * 64 + w * 16;

  f32x4 acc_k[8] = {};
  f32x4 acc_v[16] = {};
  const __bf16* xb = xt + ((size_t)b * NN + n0 + cq) * CH;
#pragma unroll
  for (int kc = 0; kc < 8; ++kc) {
    const int kb = kc * 32 + g * 8;
    bf16x8 xf = *(const bf16x8*)(xb + kb);
#pragma unroll
    for (int ct = 0; ct < 8; ++ct) {
      bf16x8 wk = *(const bf16x8*)(Wkb + (ct * 16 + cq) * CH + kb);
      acc_k[ct] = __builtin_amdgcn_mfma_f32_16x16x32_bf16(xf, wk, acc_k[ct], 0, 0, 0);
    }
#pragma unroll
    for (int et = 0; et < 16; ++et) {
      bf16x8 wv = *(const bf16x8*)(Wvb + (et * 16 + cq) * CH + kb);
      acc_v[et] = __builtin_amdgcn_mfma_f32_16x16x32_bf16(wv, xf, acc_v[et], 0, 0, 0);
    }
  }
#pragma unroll
  for (int ct = 0; ct < 8; ++ct) {
    const int col = ct * 16 + cq;
    const float bias = bk[col];
#pragma unroll
    for (int r = 0; r < 4; ++r) {
      const int n = n0 + g * 4 + r;
      K[((size_t)b * NN + n) * DQ + col] = (__bf16)(acc_k[ct][r] + bias);
    }
  }
#pragma unroll
  for (int et = 0; et < 16; ++et) {
#pragma unroll
    for (int r = 0; r < 4; ++r) {
      const int e = et * 16 + g * 4 + r;
      Vt[((size_t)b * NE + e) * NN + n0 + cq] = (__bf16)(acc_v[et][r] + bv[e]);
    }
  }
}

// ------------------------------------------------------------- attention ----
// 4 waves: wave w does QK^T+softmax for q-chunk w*16 (K from LDS, dbuf,
// gl_lds staged, swizzled) and PV for e-chunk w*64 with V fragments loaded
// DIRECT from global Vt[e][n] (reg double-buffer). P shared via LDS.
template<int KSPLIT>
__global__ __launch_bounds__(256) void attn3_k(
    const __bf16* __restrict__ Q, const __bf16* __restrict__ K,
    const __bf16* __restrict__ Vt, __bf16* __restrict__ Hout,
    float2* __restrict__ ml)
{
  __shared__ __bf16 Kt[2][32][128];   // 16 KB, chunk ^ (row&15)
  __shared__ __bf16 P[64][32];        // 4 KB,  chunk ^ ((row>>1)&3)
  __shared__ float  alphaS[64];
  __shared__ int    flagS[4];

  const int tid  = threadIdx.x;
  const int w    = tid >> 6, lane = tid & 63;
  const int cq   = lane & 15, g = lane >> 4;
  const int b    = blockIdx.y;
  const int split = (KSPLIT == 2) ? blockIdx.z : 0;
  const int n0blk = blockIdx.x * 64;
  const int nq0   = n0blk + w * 16;     // this wave's q rows (QK/softmax)
  const int e0    = w * 64;             // this wave's e chunk (PV)
  const int kvbase = split * (NN / KSPLIT);
  const int nsteps = (NN / KSPLIT) / 32;

  const __bf16* Kb  = K  + (size_t)b * NN * DQ;
  const __bf16* Vb2 = Vt + ((size_t)b * NE + e0 + cq) * NN + g * 8;

  bf16x8 qf[4];
  {
    const __bf16* Qb = Q + ((size_t)b * NN + nq0 + cq) * DQ + g * 8;
#pragma unroll
    for (int kc = 0; kc < 4; ++kc) qf[kc] = *(const bf16x8*)(Qb + kc * 32);
  }

  float m[4] = {-1e30f, -1e30f, -1e30f, -1e30f};
  float l[4] = {0.f, 0.f, 0.f, 0.f};
  f32x4 h[4][4] = {};
  bf16x8 vA[4], vB[4];

#define STAGE_K(dst, t_)                                                     \
  do {                                                                       \
    const int kv_ = kvbase + (t_) * 32;                                      \
    const __bf16* ks_ = Kb + (size_t)kv_ * DQ;                               \
    _Pragma("unroll")                                                        \
    for (int j = 0; j < 2; ++j) {                                            \
      const int D = j * 256 + tid;                                           \
      const int row = D >> 4, c0 = D & 15;                                   \
      gl_lds16(ks_ + (size_t)row * DQ + ((c0 ^ (row & 15)) << 3),            \
               &Kt[dst][0][0] + D * 8);                                      \
    }                                                                        \
  } while (0)

#define LOADV(dst, kv_)                                                      \
  do {                                                                       \
    _Pragma("unroll")                                                        \
    for (int et = 0; et < 4; ++et)                                           \
      dst[et] = *(const bf16x8*)(Vb2 + (size_t)et * 16 * NN + (kv_));        \
  } while (0)

#define STEPBODY(CUR, T_, VC, VN)                                            \
  do {                                                                       \
    if ((T_) + 1 < nsteps) {                                                 \
      STAGE_K(CUR ^ 1, (T_) + 1);                                            \
      LOADV(VN, kvbase + ((T_) + 1) * 32);                                   \
    }                                                                        \
    f32x4 s0 = {}, s1 = {};                                                  \
    _Pragma("unroll")                                                        \
    for (int kc = 0; kc < 4; ++kc) {                                         \
      bf16x8 kf0 = *(const bf16x8*)&Kt[CUR][cq][((kc * 4 + g) ^ cq) * 8];    \
      bf16x8 kf1 = *(const bf16x8*)&Kt[CUR][16 + cq][((kc * 4 + g) ^ cq) * 8]; \
      s0 = __builtin_amdgcn_mfma_f32_16x16x32_bf16(qf[kc], kf0, s0, 0, 0, 0);\
      s1 = __builtin_amdgcn_mfma_f32_16x16x32_bf16(qf[kc], kf1, s1, 0, 0, 0);\
    }                                                                        \
    float mx[4];                                                             \
    _Pragma("unroll")                                                        \
    for (int r = 0; r < 4; ++r) {                                            \
      float v = fmaxf(s0[r], s1[r]);                                         \
      v = fmaxf(v, __shfl_xor(v, 1)); v = fmaxf(v, __shfl_xor(v, 2));        \
      v = fmaxf(v, __shfl_xor(v, 4)); v = fmaxf(v, __shfl_xor(v, 8));        \
      mx[r] = v;                                                             \
    }                                                                        \
    int need_ = 0;                                                           \
    _Pragma("unroll")                                                        \
    for (int r = 0; r < 4; ++r) need_ |= (mx[r] > m[r] + 8.0f);              \
    const int nd_ = __any(need_);                                            \
    float alpha[4] = {1.f, 1.f, 1.f, 1.f};                                   \
    if (nd_) {                                                               \
      _Pragma("unroll")                                                      \
      for (int r = 0; r < 4; ++r) {                                          \
        const float mn = fmaxf(m[r], mx[r]);                                 \
        alpha[r] = __expf(m[r] - mn); m[r] = mn; l[r] *= alpha[r];           \
      }                                                                      \
    }                                                                        \
    if (cq == 0) {                                                           \
      _Pragma("unroll")                                                      \
      for (int r = 0; r < 4; ++r) alphaS[w * 16 + g * 4 + r] = alpha[r];     \
    }                                                                        \
    if (lane == 0) flagS[w] = nd_;                                           \
    float rs[4] = {0.f, 0.f, 0.f, 0.f};                                      \
    _Pragma("unroll")                                                        \
    for (int ct = 0; ct < 2; ++ct) {                                         \
      _Pragma("unroll")                                                      \
      for (int r = 0; r < 4; ++r) {                                          \
        const float sv = (ct == 0) ? s0[r] : s1[r];                          \
        const float p = __expf(sv - m[r]);                                   \
        const int grow = w * 16 + g * 4 + r;                                 \
        const int c0 = ct * 2 + (cq >> 3);                                   \
        P[grow][((c0 ^ ((grow >> 1) & 3)) << 3) + (cq & 7)] = (__bf16)p;     \
        rs[r] += p;                                                          \
      }                                                                      \
    }                                                                        \
    _Pragma("unroll")                                                        \
    for (int r = 0; r < 4; ++r) {                                            \
      rs[r] += __shfl_xor(rs[r], 1); rs[r] += __shfl_xor(rs[r], 2);          \
      rs[r] += __shfl_xor(rs[r], 4); rs[r] += __shfl_xor(rs[r], 8);          \
      l[r] += rs[r];                                                         \
    }                                                                        \
    __syncthreads();                                                         \
    const int anyf_ = flagS[0] | flagS[1] | flagS[2] | flagS[3];             \
    if (anyf_) {                                                             \
      _Pragma("unroll")                                                      \
      for (int qt = 0; qt < 4; ++qt) {                                       \
        const float a0 = alphaS[qt * 16 + g * 4 + 0];                        \
        const float a1 = alphaS[qt * 16 + g * 4 + 1];                        \
        const float a2 = alphaS[qt * 16 + g * 4 + 2];                        \
        const float a3 = alphaS[qt * 16 + g * 4 + 3];                        \
        _Pragma("unroll")                                                    \
        for (int et = 0; et < 4; ++et) {                                     \
          h[qt][et][0] *= a0; h[qt][et][1] *= a1;                            \
          h[qt][et][2] *= a2; h[qt][et][3] *= a3;                            \
        }                                                                    \
      }                                                                      \
    }                                                                        \
    _Pragma("unroll")                                                        \
    for (int qt = 0; qt < 4; ++qt) {                                         \
      const int pr = qt * 16 + cq;                                           \
      bf16x8 pf = *(const bf16x8*)&P[pr][(g ^ ((pr >> 1) & 3)) << 3];        \
      _Pragma("unroll")                                                      \
      for (int et = 0; et < 4; ++et)                                         \
        h[qt][et] = __builtin_amdgcn_mfma_f32_16x16x32_bf16(                 \
            pf, VC[et], h[qt][et], 0, 0, 0);                                 \
    }                                                                        \
    __syncthreads();                                                         \
  } while (0)

  STAGE_K(0, 0);
  LOADV(vA, kvbase);
  __syncthreads();

  for (int tp = 0; tp < nsteps; tp += 2) {
    STEPBODY(0, tp, vA, vB);
    STEPBODY(1, tp + 1, vB, vA);
  }
#undef STEPBODY
#undef LOADV
#undef STAGE_K

  if (KSPLIT == 1) {
    if (cq == 0) {
#pragma unroll
      for (int r = 0; r < 4; ++r) alphaS[w * 16 + g * 4 + r] = 1.0f / l[r];
    }
    __syncthreads();
#pragma unroll
    for (int qt = 0; qt < 4; ++qt) {
#pragma unroll
      for (int r = 0; r < 4; ++r) {
        const float iv = alphaS[qt * 16 + g * 4 + r];
        const int n = n0blk + qt * 16 + g * 4 + r;
#pragma unroll
        for (int et = 0; et < 4; ++et)
          Hout[((size_t)b * NN + n) * NE + e0 + et * 16 + cq] =
              (__bf16)(h[qt][et][r] * iv);
      }
    }
  } else {
#pragma unroll
    for (int qt = 0; qt < 4; ++qt) {
#pragma unroll
      for (int r = 0; r < 4; ++r) {
        const int n = n0blk + qt * 16 + g * 4 + r;
#pragma unroll
        for (int et = 0; et < 4; ++et)
          Hout[(((size_t)split * NB + b) * NN + n) * NE + e0 + et * 16 + cq] =
              (__bf16)h[qt][et][r];
      }
    }
    if (cq == 0) {
#pragma unroll
      for (int r = 0; r < 4; ++r)
        ml[((size_t)split * NB + b) * NN + nq0 + g * 4 + r] = make_float2(m[r], l[r]);
    }
  }
}

// ------------------------------------------------------------- combine ------
__global__ __launch_bounds__(256) void combine_k(
    const __bf16* __restrict__ Hp, const float2* __restrict__ ml,
    __bf16* __restrict__ H)
{
  const int row = blockIdx.x * 8 + (threadIdx.x >> 5);   // flat (b,n)
  const int e0  = (threadIdx.x & 31) * 8;
  const float2 a = ml[row];
  const float2 c = ml[(size_t)NB * NN + row];
  const float M  = fmaxf(a.x, c.x);
  const float w0 = __expf(a.x - M), w1 = __expf(c.x - M);
  const float inv = 1.0f / (w0 * a.y + w1 * c.y);
  bf16x8 h0 = *(const bf16x8*)(Hp + (size_t)row * NE + e0);
  bf16x8 h1 = *(const bf16x8*)(Hp + ((size_t)NB * NN + row) * NE + e0);
  bf16x8 o;
#pragma unroll
  for (int i = 0; i < 8; ++i)
    o[i] = (__bf16)((w0 * (float)h0[i] + w1 * (float)h1[i]) * inv);
  *(bf16x8*)(H + (size_t)row * NE + e0) = o;
}

// ------------------------------------------------------------ out proj ------
// swapped operands: D[f][n] = Wo . H^T  -> coalesced fp32 stores along n
__global__ __launch_bounds__(256) void outproj_k(
    const __bf16* __restrict__ H, const __bf16* __restrict__ Wob,
    const float* __restrict__ bo, const float* __restrict__ x,
    float* __restrict__ out)
{
  const int b    = blockIdx.y;
  const int w    = threadIdx.x >> 6;
  const int lane = threadIdx.x & 63;
  const int cq   = lane & 15, g = lane >> 4;
  const int n0   = blockIdx.x * 64 + w * 16;

  f32x4 acc[16] = {};
  const __bf16* Hb = H + ((size_t)b * NN + n0 + cq) * NE;
#pragma unroll
  for (int kc = 0; kc < 8; ++kc) {
    const int kb = kc * 32 + g * 8;
    bf16x8 hf = *(const bf16x8*)(Hb + kb);
#pragma unroll
    for (int ft = 0; ft < 16; ++ft) {
      bf16x8 wo = *(const bf16x8*)(Wob + (ft * 16 + cq) * CH + kb);
      acc[ft] = __builtin_amdgcn_mfma_f32_16x16x32_bf16(wo, hf, acc[ft], 0, 0, 0);
    }
  }
#pragma unroll
  for (int ft = 0; ft < 16; ++ft) {
#pragma unroll
    for (int r = 0; r < 4; ++r) {
      const int f = ft * 16 + g * 4 + r;
      const size_t idx = ((size_t)b * CH + f) * NN + n0 + cq;
      out[idx] = x[idx] + acc[ft][r] + bo[f];
    }
  }
}

// ----------------------------------------------------------------------------
extern "C" void kernel_launch(void* const* d_in, const int* in_sizes, int n_in,
                              void* d_out, int out_size, void* d_ws, size_t ws_size,
                              hipStream_t stream) {
  const float* x  = (const float*)d_in[0];
  const float* y  = (const float*)d_in[1];
  const float* Wq = (const float*)d_in[2];
  const float* bq = (const float*)d_in[3];
  const float* Wk = (const float*)d_in[4];
  const float* bk = (const float*)d_in[5];
  const float* Wv = (const float*)d_in[6];
  const float* bv = (const float*)d_in[7];
  const float* Wo = (const float*)d_in[8];
  const float* bo = (const float*)d_in[9];
  float* out = (float*)d_out;

  char* ws = (char*)d_ws;
  __bf16* xt = (__bf16*)(ws);                        // 16 MB [b][n][c]
  __bf16* yt = (__bf16*)(ws + ((size_t)16 << 20));   // 16 MB [b][n][c]
  __bf16* Q  = (__bf16*)(ws + ((size_t)32 << 20));   //  8 MB [b][n][128]
  __bf16* K  = (__bf16*)(ws + ((size_t)40 << 20));   //  8 MB [b][n][128]
  __bf16* Vt = (__bf16*)(ws + ((size_t)48 << 20));   // 16 MB [b][e][n]
  __bf16* Wb = (__bf16*)(ws + ((size_t)64 << 20));   // 384 KB bf16 weights
  float2* ml = (float2*)(ws + ((size_t)64 << 20) + 393216);  // 512 KB
  __bf16* Hp = xt;                                   // 32 MB partials (xt+yt dead)
  __bf16* Hf = Q;                                    // 16 MB final H (Q+K dead)
  __bf16* Wqb = Wb, *Wkb = Wb + 32768, *Wvb = Wb + 65536, *Wob = Wb + 131072;

  dim3 grid(64, 8), blk(256);
  wprep_k  <<<dim3(192), blk, 0, stream>>>(Wq, Wk, Wv, Wo, Wb);
  xyprep_k <<<dim3(64, 8, 2), blk, 0, stream>>>(x, y, xt, yt);
  proj_q_k <<<grid, blk, 0, stream>>>(yt, Wqb, bq, Q);
  proj_kv_k<<<grid, blk, 0, stream>>>(xt, Wkb, bk, Wvb, bv, K, Vt);

  const size_t need = ((size_t)64 << 20) + 393216
                    + (size_t)2 * NB * NN * sizeof(float2);
  if (ws_size >= need) {
    attn3_k<2><<<dim3(64, 8, 2), blk, 0, stream>>>(Q, K, Vt, Hp, ml);
    combine_k<<<dim3(NB * NN / 8), blk, 0, stream>>>(Hp, ml, Hf);
    outproj_k<<<grid, blk, 0, stream>>>(Hf, Wob, bo, x, out);
  } else {
    attn3_k<1><<<dim3(64, 8, 1), blk, 0, stream>>>(Q, K, Vt, xt, nullptr);
    outproj_k<<<grid, blk, 0, stream>>>(xt, Wob, bo, x, out);
  }
}

// Round 6
// 359.817 us; speedup vs baseline: 1.3876x; 1.3876x over previous
//
#include <hip/hip_runtime.h>
#include <hip/hip_bf16.h>
#include <stdint.h>

#define NB 8
#define CH 256
#define DQ 128
#define NE 256
#define NN 4096

using bf16x8 = __attribute__((ext_vector_type(8))) __bf16;
using bf16x4 = __attribute__((ext_vector_type(4))) __bf16;
using f32x4  = __attribute__((ext_vector_type(4))) float;

__device__ __forceinline__ void gl_lds16(const void* g, void* l){
  __builtin_amdgcn_global_load_lds(
      (const __attribute__((address_space(1))) unsigned int*)g,
      (__attribute__((address_space(3))) unsigned int*)l, 16, 0, 0);
}

// -------------------------------------------------------- weight prep -------
__global__ __launch_bounds__(256) void wprep_k(
    const float* __restrict__ Wq, const float* __restrict__ Wk,
    const float* __restrict__ Wv, const float* __restrict__ Wo,
    __bf16* __restrict__ Wb)
{
  const int bidx = blockIdx.x;
  const float* s4;  __bf16* d;  int i = bidx * 256 + threadIdx.x;
  if (bidx < 32)       { s4 = Wq; d = Wb;          }
  else if (bidx < 64)  { s4 = Wk; d = Wb + 32768;  i -= 32 * 256; }
  else if (bidx < 128) { s4 = Wv; d = Wb + 65536;  i -= 64 * 256; }
  else                 { s4 = Wo; d = Wb + 131072; i -= 128 * 256; }
  float4 v = ((const float4*)s4)[i];
  bf16x4 o; o[0]=(__bf16)v.x; o[1]=(__bf16)v.y; o[2]=(__bf16)v.z; o[3]=(__bf16)v.w;
  *(bf16x4*)(d + i * 4) = o;
}

// ------------------------------------------------- x/y transpose + cvt ------
__global__ __launch_bounds__(256) void xyprep_k(
    const float* __restrict__ x, const float* __restrict__ y,
    __bf16* __restrict__ xt, __bf16* __restrict__ yt)
{
  const int b = blockIdx.y;
  const float* src = blockIdx.z ? y : x;
  __bf16* dst      = blockIdx.z ? yt : xt;
  const int n    = blockIdx.x * 64 + (threadIdx.x & 63);
  const int cgrp = threadIdx.x >> 6;
  const float* sb = src + (size_t)b * CH * NN + n;
  __bf16* db = dst + ((size_t)b * NN + n) * CH;
#pragma unroll
  for (int cc = 0; cc < 8; ++cc) {
    const int c0 = cgrp * 64 + cc * 8;
    bf16x8 o;
#pragma unroll
    for (int s = 0; s < 8; ++s) o[s] = (__bf16)sb[(size_t)(c0 + s) * NN];
    *(bf16x8*)(db + c0) = o;
  }
}

// ---------------------------------------------------------------- proj Q ----
__global__ __launch_bounds__(256) void proj_q_k(
    const __bf16* __restrict__ yt, const __bf16* __restrict__ Wqb,
    const float* __restrict__ bq, __bf16* __restrict__ Q)
{
  const int b    = blockIdx.y;
  const int w    = threadIdx.x >> 6;
  const int lane = threadIdx.x & 63;
  const int cq   = lane & 15, g = lane >> 4;
  const int n0   = blockIdx.x * 64 + w * 16;
  const float scale = 0.08838834764831845f;  // 1/sqrt(128)

  f32x4 acc[8] = {};
  const __bf16* yb = yt + ((size_t)b * NN + n0 + cq) * CH;
#pragma unroll
  for (int kc = 0; kc < 8; ++kc) {
    const int kb = kc * 32 + g * 8;
    bf16x8 af = *(const bf16x8*)(yb + kb);
#pragma unroll
    for (int ct = 0; ct < 8; ++ct) {
      bf16x8 bfr = *(const bf16x8*)(Wqb + (ct * 16 + cq) * CH + kb);
      acc[ct] = __builtin_amdgcn_mfma_f32_16x16x32_bf16(af, bfr, acc[ct], 0, 0, 0);
    }
  }
#pragma unroll
  for (int ct = 0; ct < 8; ++ct) {
    const int col = ct * 16 + cq;
    const float bias = bq[col];
#pragma unroll
    for (int r = 0; r < 4; ++r) {
      const int n = n0 + g * 4 + r;
      Q[((size_t)b * NN + n) * DQ + col] = (__bf16)((acc[ct][r] + bias) * scale);
    }
  }
}

// --------------------------------------------------------------- proj KV ----
__global__ __launch_bounds__(256) void proj_kv_k(
    const __bf16* __restrict__ xt,
    const __bf16* __restrict__ Wkb, const float* __restrict__ bk,
    const __bf16* __restrict__ Wvb, const float* __restrict__ bv,
    __bf16* __restrict__ K, __bf16* __restrict__ Vt)
{
  const int b    = blockIdx.y;
  const int w    = threadIdx.x >> 6;
  const int lane = threadIdx.x & 63;
  const int cq   = lane & 15, g = lane >> 4;
  const int n0   = blockIdx.x * 64 + w * 16;

  f32x4 acc_k[8] = {};
  f32x4 acc_v[16] = {};
  const __bf16* xb = xt + ((size_t)b * NN + n0 + cq) * CH;
#pragma unroll
  for (int kc = 0; kc < 8; ++kc) {
    const int kb = kc * 32 + g * 8;
    bf16x8 xf = *(const bf16x8*)(xb + kb);
#pragma unroll
    for (int ct = 0; ct < 8; ++ct) {
      bf16x8 wk = *(const bf16x8*)(Wkb + (ct * 16 + cq) * CH + kb);
      acc_k[ct] = __builtin_amdgcn_mfma_f32_16x16x32_bf16(xf, wk, acc_k[ct], 0, 0, 0);
    }
#pragma unroll
    for (int et = 0; et < 16; ++et) {
      bf16x8 wv = *(const bf16x8*)(Wvb + (et * 16 + cq) * CH + kb);
      acc_v[et] = __builtin_amdgcn_mfma_f32_16x16x32_bf16(wv, xf, acc_v[et], 0, 0, 0);
    }
  }
#pragma unroll
  for (int ct = 0; ct < 8; ++ct) {
    const int col = ct * 16 + cq;
    const float bias = bk[col];
#pragma unroll
    for (int r = 0; r < 4; ++r) {
      const int n = n0 + g * 4 + r;
      K[((size_t)b * NN + n) * DQ + col] = (__bf16)(acc_k[ct][r] + bias);
    }
  }
#pragma unroll
  for (int et = 0; et < 16; ++et) {
#pragma unroll
    for (int r = 0; r < 4; ++r) {
      const int e = et * 16 + g * 4 + r;
      Vt[((size_t)b * NE + e) * NN + n0 + cq] = (__bf16)(acc_v[et][r] + bv[e]);
    }
  }
}

// ------------------------------------------------------------- attention ----
// 4 waves x 32 q-rows, KVBLK=32. Swapped QK (mfma(K,Q) -> S^T): softmax is
// lane-local per q-column. P re-fragmented through per-wave LDS tile (pad-80B,
// conflict-free). K/V tiles LDS-staged via gl_lds, double buffered, swizzled.
template<int KSPLIT>
__global__ __launch_bounds__(256, 2) void attn4_k(
    const __bf16* __restrict__ Q, const __bf16* __restrict__ K,
    const __bf16* __restrict__ Vt, __bf16* __restrict__ Hout,
    float2* __restrict__ ml)
{
  __shared__ __bf16 Kt[2][32][128];   // 16 KB, chunk ^ (row&15)
  __shared__ __bf16 Vs[2][256][32];   // 32 KB, chunk ^ ((e>>1)&3)
  __shared__ __bf16 Pw[4][32][40];    // 10 KB, per-wave P tile (pad 80B)

  const int tid  = threadIdx.x;
  const int w    = tid >> 6, lane = tid & 63;
  const int cq   = lane & 15, g = lane >> 4;
  const int b    = blockIdx.y;
  const int split = (KSPLIT == 2) ? blockIdx.z : 0;
  const int n0   = blockIdx.x * 128 + w * 32;     // this wave's 32 q rows
  const int kvbase = split * (NN / KSPLIT);
  const int nsteps = (NN / KSPLIT) / 32;

  const __bf16* Kb = K  + (size_t)b * NN * DQ;
  const __bf16* Vb = Vt + (size_t)b * NE * NN;

  bf16x8 qf[2][4];
#pragma unroll
  for (int qt = 0; qt < 2; ++qt) {
    const __bf16* Qb = Q + ((size_t)b * NN + n0 + qt * 16 + cq) * DQ + g * 8;
#pragma unroll
    for (int kc = 0; kc < 4; ++kc) qf[qt][kc] = *(const bf16x8*)(Qb + kc * 32);
  }

  float m[2] = {-1e30f, -1e30f};
  float l[2] = {0.f, 0.f};
  f32x4 h[2][16] = {};

#define STAGE(dst, t_)                                                       \
  do {                                                                       \
    const int kv_ = kvbase + (t_) * 32;                                      \
    const __bf16* ks_ = Kb + (size_t)kv_ * DQ;                               \
    _Pragma("unroll")                                                        \
    for (int j = 0; j < 2; ++j) {                                            \
      const int D = j * 256 + tid;                                           \
      const int row = D >> 4, c0 = D & 15;                                   \
      gl_lds16(ks_ + (size_t)row * DQ + ((c0 ^ (row & 15)) << 3),            \
               &Kt[dst][0][0] + D * 8);                                      \
    }                                                                        \
    _Pragma("unroll")                                                        \
    for (int j = 0; j < 4; ++j) {                                            \
      const int D = j * 256 + tid;                                           \
      const int e = D >> 2, c0 = D & 3;                                      \
      gl_lds16(Vb + (size_t)e * NN + kv_ + ((c0 ^ ((e >> 1) & 3)) << 3),     \
               &Vs[dst][0][0] + D * 8);                                      \
    }                                                                        \
  } while (0)

  STAGE(0, 0);
  __syncthreads();
  int cur = 0;

  for (int t = 0; t < nsteps; ++t) {
    if (t + 1 < nsteps) STAGE(cur ^ 1, t + 1);

    // ---- QK^T swapped: s[qt][kt][r] = S[kv=kt*16+g*4+r][q=qt*16+cq]
    f32x4 s00 = {}, s01 = {}, s10 = {}, s11 = {};
#pragma unroll
    for (int kc = 0; kc < 4; ++kc) {
      bf16x8 kf0 = *(const bf16x8*)&Kt[cur][cq][((kc * 4 + g) ^ cq) * 8];
      bf16x8 kf1 = *(const bf16x8*)&Kt[cur][16 + cq][((kc * 4 + g) ^ cq) * 8];
      s00 = __builtin_amdgcn_mfma_f32_16x16x32_bf16(kf0, qf[0][kc], s00, 0, 0, 0);
      s01 = __builtin_amdgcn_mfma_f32_16x16x32_bf16(kf1, qf[0][kc], s01, 0, 0, 0);
      s10 = __builtin_amdgcn_mfma_f32_16x16x32_bf16(kf0, qf[1][kc], s10, 0, 0, 0);
      s11 = __builtin_amdgcn_mfma_f32_16x16x32_bf16(kf1, qf[1][kc], s11, 0, 0, 0);
    }
    // ---- lane-local max per q-column (reduce over g groups only)
    float mx0 = fmaxf(fmaxf(fmaxf(s00[0], s00[1]), fmaxf(s00[2], s00[3])),
                      fmaxf(fmaxf(s01[0], s01[1]), fmaxf(s01[2], s01[3])));
    float mx1 = fmaxf(fmaxf(fmaxf(s10[0], s10[1]), fmaxf(s10[2], s10[3])),
                      fmaxf(fmaxf(s11[0], s11[1]), fmaxf(s11[2], s11[3])));
    mx0 = fmaxf(mx0, __shfl_xor(mx0, 16)); mx0 = fmaxf(mx0, __shfl_xor(mx0, 32));
    mx1 = fmaxf(mx1, __shfl_xor(mx1, 16)); mx1 = fmaxf(mx1, __shfl_xor(mx1, 32));

    // ---- defer-max rescale (THR=8)
    if (__any((mx0 > m[0] + 8.0f) | (mx1 > m[1] + 8.0f))) {
      float al[2];
      const float mn0 = fmaxf(m[0], mx0), mn1 = fmaxf(m[1], mx1);
      al[0] = __expf(m[0] - mn0); m[0] = mn0; l[0] *= al[0];
      al[1] = __expf(m[1] - mn1); m[1] = mn1; l[1] *= al[1];
#pragma unroll
      for (int qt = 0; qt < 2; ++qt) {
        float ar[4];
#pragma unroll
        for (int r = 0; r < 4; ++r) ar[r] = __shfl(al[qt], g * 4 + r);
#pragma unroll
        for (int et = 0; et < 16; ++et) {
          h[qt][et][0] *= ar[0]; h[qt][et][1] *= ar[1];
          h[qt][et][2] *= ar[2]; h[qt][et][3] *= ar[3];
        }
      }
    }
    // ---- exp + row-sum + P pack/write (per-wave LDS tile, no barrier)
#pragma unroll
    for (int qt = 0; qt < 2; ++qt) {
      const f32x4 sa = qt ? s10 : s00;
      const f32x4 sb = qt ? s11 : s01;
      float p0[4], p1[4];
#pragma unroll
      for (int r = 0; r < 4; ++r) { p0[r] = __expf(sa[r] - m[qt]); }
#pragma unroll
      for (int r = 0; r < 4; ++r) { p1[r] = __expf(sb[r] - m[qt]); }
      float rs = (p0[0] + p0[1]) + (p0[2] + p0[3])
               + (p1[0] + p1[1]) + (p1[2] + p1[3]);
      rs += __shfl_xor(rs, 16); rs += __shfl_xor(rs, 32);
      l[qt] += rs;
      bf16x4 w0, w1;
#pragma unroll
      for (int r = 0; r < 4; ++r) { w0[r] = (__bf16)p0[r]; w1[r] = (__bf16)p1[r]; }
      *(bf16x4*)&Pw[w][qt * 16 + cq][g * 4]      = w0;
      *(bf16x4*)&Pw[w][qt * 16 + cq][16 + g * 4] = w1;
    }
    // ---- re-fragment P and run PV
    bf16x8 pa0 = *(const bf16x8*)&Pw[w][cq][g * 8];
    bf16x8 pa1 = *(const bf16x8*)&Pw[w][16 + cq][g * 8];
#pragma unroll
    for (int et = 0; et < 16; ++et) {
      bf16x8 vf = *(const bf16x8*)&Vs[cur][et * 16 + cq][(g ^ ((cq >> 1) & 3)) * 8];
      h[0][et] = __builtin_amdgcn_mfma_f32_16x16x32_bf16(pa0, vf, h[0][et], 0, 0, 0);
      h[1][et] = __builtin_amdgcn_mfma_f32_16x16x32_bf16(pa1, vf, h[1][et], 0, 0, 0);
    }
    __syncthreads();
    cur ^= 1;
  }
#undef STAGE

  if (KSPLIT == 1) {
#pragma unroll
    for (int qt = 0; qt < 2; ++qt) {
      const float inv = 1.0f / l[qt];
      float ir[4];
#pragma unroll
      for (int r = 0; r < 4; ++r) ir[r] = __shfl(inv, g * 4 + r);
#pragma unroll
      for (int et = 0; et < 16; ++et) {
#pragma unroll
        for (int r = 0; r < 4; ++r) {
          const int n = n0 + qt * 16 + g * 4 + r;
          Hout[((size_t)b * NN + n) * NE + et * 16 + cq] =
              (__bf16)(h[qt][et][r] * ir[r]);
        }
      }
    }
  } else {
#pragma unroll
    for (int qt = 0; qt < 2; ++qt) {
#pragma unroll
      for (int et = 0; et < 16; ++et) {
#pragma unroll
        for (int r = 0; r < 4; ++r) {
          const int n = n0 + qt * 16 + g * 4 + r;
          Hout[(((size_t)split * NB + b) * NN + n) * NE + et * 16 + cq] =
              (__bf16)h[qt][et][r];
        }
      }
    }
    if (g == 0) {
#pragma unroll
      for (int qt = 0; qt < 2; ++qt)
        ml[((size_t)split * NB + b) * NN + n0 + qt * 16 + cq] =
            make_float2(m[qt], l[qt]);
    }
  }
}

// --------------------------------------------- out proj (+fused combine) ----
// swapped operands: D[f][n] = Wo . H^T; split-combine done inline per n-col.
template<int KS>
__global__ __launch_bounds__(256) void outproj_k(
    const __bf16* __restrict__ Hp, const float2* __restrict__ ml,
    const __bf16* __restrict__ Wob, const float* __restrict__ bo,
    const float* __restrict__ x, float* __restrict__ out)
{
  const int b    = blockIdx.y;
  const int w    = threadIdx.x >> 6;
  const int lane = threadIdx.x & 63;
  const int cq   = lane & 15, g = lane >> 4;
  const int n0   = blockIdx.x * 64 + w * 16;

  const size_t row = (size_t)b * NN + n0 + cq;
  float w0 = 1.f, w1 = 0.f;
  const __bf16* Hb0 = Hp + row * NE;
  const __bf16* Hb1 = Hb0;
  if (KS == 2) {
    const float2 a = ml[row];
    const float2 c = ml[(size_t)NB * NN + row];
    const float M  = fmaxf(a.x, c.x);
    const float e0 = __expf(a.x - M), e1 = __expf(c.x - M);
    const float inv = 1.0f / (e0 * a.y + e1 * c.y);
    w0 = e0 * inv; w1 = e1 * inv;
    Hb1 = Hp + ((size_t)NB * NN + row) * NE;
  }

  f32x4 acc[16] = {};
#pragma unroll
  for (int kc = 0; kc < 8; ++kc) {
    const int kb = kc * 32 + g * 8;
    bf16x8 h0 = *(const bf16x8*)(Hb0 + kb);
    bf16x8 hf;
    if (KS == 2) {
      bf16x8 h1 = *(const bf16x8*)(Hb1 + kb);
#pragma unroll
      for (int s = 0; s < 8; ++s)
        hf[s] = (__bf16)(w0 * (float)h0[s] + w1 * (float)h1[s]);
    } else {
      hf = h0;
    }
#pragma unroll
    for (int ft = 0; ft < 16; ++ft) {
      bf16x8 wo = *(const bf16x8*)(Wob + (ft * 16 + cq) * CH + kb);
      acc[ft] = __builtin_amdgcn_mfma_f32_16x16x32_bf16(wo, hf, acc[ft], 0, 0, 0);
    }
  }
#pragma unroll
  for (int ft = 0; ft < 16; ++ft) {
#pragma unroll
    for (int r = 0; r < 4; ++r) {
      const int f = ft * 16 + g * 4 + r;
      const size_t idx = ((size_t)b * CH + f) * NN + n0 + cq;
      out[idx] = x[idx] + acc[ft][r] + bo[f];
    }
  }
}

// ----------------------------------------------------------------------------
extern "C" void kernel_launch(void* const* d_in, const int* in_sizes, int n_in,
                              void* d_out, int out_size, void* d_ws, size_t ws_size,
                              hipStream_t stream) {
  const float* x  = (const float*)d_in[0];
  const float* y  = (const float*)d_in[1];
  const float* Wq = (const float*)d_in[2];
  const float* bq = (const float*)d_in[3];
  const float* Wk = (const float*)d_in[4];
  const float* bk = (const float*)d_in[5];
  const float* Wv = (const float*)d_in[6];
  const float* bv = (const float*)d_in[7];
  const float* Wo = (const float*)d_in[8];
  const float* bo = (const float*)d_in[9];
  float* out = (float*)d_out;

  char* ws = (char*)d_ws;
  __bf16* xt = (__bf16*)(ws);                        // 16 MB [b][n][c]
  __bf16* yt = (__bf16*)(ws + ((size_t)16 << 20));   // 16 MB [b][n][c]
  __bf16* Q  = (__bf16*)(ws + ((size_t)32 << 20));   //  8 MB [b][n][128]
  __bf16* K  = (__bf16*)(ws + ((size_t)40 << 20));   //  8 MB [b][n][128]
  __bf16* Vt = (__bf16*)(ws + ((size_t)48 << 20));   // 16 MB [b][e][n]
  __bf16* Wb = (__bf16*)(ws + ((size_t)64 << 20));   // 384 KB bf16 weights
  float2* ml = (float2*)(ws + ((size_t)64 << 20) + 393216);  // 512 KB
  __bf16* Hp = xt;                                   // 32 MB partials (xt+yt dead)
  __bf16* Wqb = Wb, *Wkb = Wb + 32768, *Wvb = Wb + 65536, *Wob = Wb + 131072;

  dim3 grid(64, 8), blk(256);
  wprep_k  <<<dim3(192), blk, 0, stream>>>(Wq, Wk, Wv, Wo, Wb);
  xyprep_k <<<dim3(64, 8, 2), blk, 0, stream>>>(x, y, xt, yt);
  proj_q_k <<<grid, blk, 0, stream>>>(yt, Wqb, bq, Q);
  proj_kv_k<<<grid, blk, 0, stream>>>(xt, Wkb, bk, Wvb, bv, K, Vt);

  const size_t need = ((size_t)64 << 20) + 393216
                    + (size_t)2 * NB * NN * sizeof(float2);
  if (ws_size >= need) {
    attn4_k<2><<<dim3(32, 8, 2), blk, 0, stream>>>(Q, K, Vt, Hp, ml);
    outproj_k<2><<<grid, blk, 0, stream>>>(Hp, ml, Wob, bo, x, out);
  } else {
    attn4_k<1><<<dim3(32, 8, 1), blk, 0, stream>>>(Q, K, Vt, Hp, nullptr);
    outproj_k<1><<<grid, blk, 0, stream>>>(Hp, nullptr, Wob, bo, x, out);
  }
}

// Round 7
// 346.087 us; speedup vs baseline: 1.4427x; 1.0397x over previous
//
#include <hip/hip_runtime.h>
#include <hip/hip_bf16.h>
#include <stdint.h>

#define NB 8
#define CH 256
#define DQ 128
#define NE 256
#define NN 4096

using bf16x8 = __attribute__((ext_vector_type(8))) __bf16;
using bf16x4 = __attribute__((ext_vector_type(4))) __bf16;
using f32x4  = __attribute__((ext_vector_type(4))) float;

__device__ __forceinline__ void gl_lds16(const void* g, void* l){
  __builtin_amdgcn_global_load_lds(
      (const __attribute__((address_space(1))) unsigned int*)g,
      (__attribute__((address_space(3))) unsigned int*)l, 16, 0, 0);
}

// -------------------------------------------------------- weight prep -------
__global__ __launch_bounds__(256) void wprep_k(
    const float* __restrict__ Wq, const float* __restrict__ Wk,
    const float* __restrict__ Wv, const float* __restrict__ Wo,
    __bf16* __restrict__ Wb)
{
  const int bidx = blockIdx.x;
  const float* s4;  __bf16* d;  int i = bidx * 256 + threadIdx.x;
  if (bidx < 32)       { s4 = Wq; d = Wb;          }
  else if (bidx < 64)  { s4 = Wk; d = Wb + 32768;  i -= 32 * 256; }
  else if (bidx < 128) { s4 = Wv; d = Wb + 65536;  i -= 64 * 256; }
  else                 { s4 = Wo; d = Wb + 131072; i -= 128 * 256; }
  float4 v = ((const float4*)s4)[i];
  bf16x4 o; o[0]=(__bf16)v.x; o[1]=(__bf16)v.y; o[2]=(__bf16)v.z; o[3]=(__bf16)v.w;
  *(bf16x4*)(d + i * 4) = o;
}

// ----------------------------------------------- fused projections ----------
// Stages x,y tiles [64n x 256c] through swizzled LDS (transpose+cvt), then
// computes Q (from y), K and Vt (from x, Vt via swapped operands) with MFMA.
__global__ __launch_bounds__(256) void projall_k(
    const float* __restrict__ x, const float* __restrict__ y,
    const __bf16* __restrict__ Wqb, const float* __restrict__ bq,
    const __bf16* __restrict__ Wkb, const float* __restrict__ bk,
    const __bf16* __restrict__ Wvb, const float* __restrict__ bv,
    __bf16* __restrict__ Q, __bf16* __restrict__ K, __bf16* __restrict__ Vt)
{
  __shared__ __bf16 Xs[64 * 256];   // 32 KB, chunk ^= (row&15)
  __shared__ __bf16 Ys[64 * 256];   // 32 KB

  const int tid = threadIdx.x;
  const int b   = blockIdx.y;
  const int n0  = blockIdx.x * 64;

  // ---- staging: thread owns n-row (tid&63), c-groups (tid>>6)+4i
  {
    const int ln = tid & 63;
    const int cg = tid >> 6;
    const float* xb = x + (size_t)b * CH * NN + n0 + ln;
    const float* yb = y + (size_t)b * CH * NN + n0 + ln;
#pragma unroll
    for (int i = 0; i < 8; ++i) {
      const int c8 = cg + i * 4;
      const int c0 = c8 * 8;
      bf16x8 ox, oy;
#pragma unroll
      for (int s = 0; s < 8; ++s) {
        ox[s] = (__bf16)xb[(size_t)(c0 + s) * NN];
        oy[s] = (__bf16)yb[(size_t)(c0 + s) * NN];
      }
      const int ch = c8 ^ (ln & 15);
      *(bf16x8*)&Xs[(ln * 32 + ch) * 8] = ox;
      *(bf16x8*)&Ys[(ln * 32 + ch) * 8] = oy;
    }
  }
  __syncthreads();

  const int w    = tid >> 6;
  const int lane = tid & 63;
  const int cq   = lane & 15, g = lane >> 4;
  const int nw   = n0 + w * 16;          // this wave's 16 output rows
  const float scale = 0.08838834764831845f;  // 1/sqrt(128)

  // A-frag: row = w*16+cq, chunk = (kc*4+g) ^ cq  (row&15 == cq)
#define LDA(S, kc) (*(const bf16x8*)&S[(((w * 16 + cq) * 32) + (((kc) * 4 + g) ^ cq)) * 8])

  // ---- Q from y-tile
  {
    f32x4 acc[8] = {};
#pragma unroll
    for (int kc = 0; kc < 8; ++kc) {
      bf16x8 af = LDA(Ys, kc);
#pragma unroll
      for (int ct = 0; ct < 8; ++ct) {
        bf16x8 bfr = *(const bf16x8*)(Wqb + (ct * 16 + cq) * CH + kc * 32 + g * 8);
        acc[ct] = __builtin_amdgcn_mfma_f32_16x16x32_bf16(af, bfr, acc[ct], 0, 0, 0);
      }
    }
#pragma unroll
    for (int ct = 0; ct < 8; ++ct) {
      const int col = ct * 16 + cq;
      const float bias = bq[col];
#pragma unroll
      for (int r = 0; r < 4; ++r) {
        const int n = nw + g * 4 + r;
        Q[((size_t)b * NN + n) * DQ + col] = (__bf16)((acc[ct][r] + bias) * scale);
      }
    }
  }

  // ---- K + V from x-tile (share xf loads)
  {
    f32x4 acc_k[8] = {};
    f32x4 acc_v[16] = {};
#pragma unroll
    for (int kc = 0; kc < 8; ++kc) {
      bf16x8 xf = LDA(Xs, kc);
#pragma unroll
      for (int ct = 0; ct < 8; ++ct) {
        bf16x8 wk = *(const bf16x8*)(Wkb + (ct * 16 + cq) * CH + kc * 32 + g * 8);
        acc_k[ct] = __builtin_amdgcn_mfma_f32_16x16x32_bf16(xf, wk, acc_k[ct], 0, 0, 0);
      }
#pragma unroll
      for (int et = 0; et < 16; ++et) {
        bf16x8 wv = *(const bf16x8*)(Wvb + (et * 16 + cq) * CH + kc * 32 + g * 8);
        acc_v[et] = __builtin_amdgcn_mfma_f32_16x16x32_bf16(wv, xf, acc_v[et], 0, 0, 0);
      }
    }
#pragma unroll
    for (int ct = 0; ct < 8; ++ct) {
      const int col = ct * 16 + cq;
      const float bias = bk[col];
#pragma unroll
      for (int r = 0; r < 4; ++r) {
        const int n = nw + g * 4 + r;
        K[((size_t)b * NN + n) * DQ + col] = (__bf16)(acc_k[ct][r] + bias);
      }
    }
#pragma unroll
    for (int et = 0; et < 16; ++et) {
#pragma unroll
      for (int r = 0; r < 4; ++r) {
        const int e = et * 16 + g * 4 + r;
        Vt[((size_t)b * NE + e) * NN + nw + cq] = (__bf16)(acc_v[et][r] + bv[e]);
      }
    }
  }
#undef LDA
}

// ------------------------------------------------------------- attention ----
// 4 waves x 32 q-rows, KVBLK=32. Swapped QK (mfma(K,Q) -> S^T): softmax is
// lane-local per q-column. P re-fragmented through per-wave LDS tile (pad-80B,
// conflict-free). K/V tiles LDS-staged via gl_lds, double buffered, swizzled.
template<int KSPLIT>
__global__ __launch_bounds__(256, 2) void attn4_k(
    const __bf16* __restrict__ Q, const __bf16* __restrict__ K,
    const __bf16* __restrict__ Vt, __bf16* __restrict__ Hout,
    float2* __restrict__ ml)
{
  __shared__ __bf16 Kt[2][32][128];   // 16 KB, chunk ^ (row&15)
  __shared__ __bf16 Vs[2][256][32];   // 32 KB, chunk ^ ((e>>1)&3)
  __shared__ __bf16 Pw[4][32][40];    // 10 KB, per-wave P tile (pad 80B)

  const int tid  = threadIdx.x;
  const int w    = tid >> 6, lane = tid & 63;
  const int cq   = lane & 15, g = lane >> 4;
  const int b    = blockIdx.y;
  const int split = (KSPLIT == 2) ? blockIdx.z : 0;
  const int n0   = blockIdx.x * 128 + w * 32;     // this wave's 32 q rows
  const int kvbase = split * (NN / KSPLIT);
  const int nsteps = (NN / KSPLIT) / 32;

  const __bf16* Kb = K  + (size_t)b * NN * DQ;
  const __bf16* Vb = Vt + (size_t)b * NE * NN;

  bf16x8 qf[2][4];
#pragma unroll
  for (int qt = 0; qt < 2; ++qt) {
    const __bf16* Qb = Q + ((size_t)b * NN + n0 + qt * 16 + cq) * DQ + g * 8;
#pragma unroll
    for (int kc = 0; kc < 4; ++kc) qf[qt][kc] = *(const bf16x8*)(Qb + kc * 32);
  }

  float m[2] = {-1e30f, -1e30f};
  float l[2] = {0.f, 0.f};
  f32x4 h[2][16] = {};

#define STAGE(dst, t_)                                                       \
  do {                                                                       \
    const int kv_ = kvbase + (t_) * 32;                                      \
    const __bf16* ks_ = Kb + (size_t)kv_ * DQ;                               \
    _Pragma("unroll")                                                        \
    for (int j = 0; j < 2; ++j) {                                            \
      const int D = j * 256 + tid;                                           \
      const int row = D >> 4, c0 = D & 15;                                   \
      gl_lds16(ks_ + (size_t)row * DQ + ((c0 ^ (row & 15)) << 3),            \
               &Kt[dst][0][0] + D * 8);                                      \
    }                                                                        \
    _Pragma("unroll")                                                        \
    for (int j = 0; j < 4; ++j) {                                            \
      const int D = j * 256 + tid;                                           \
      const int e = D >> 2, c0 = D & 3;                                      \
      gl_lds16(Vb + (size_t)e * NN + kv_ + ((c0 ^ ((e >> 1) & 3)) << 3),     \
               &Vs[dst][0][0] + D * 8);                                      \
    }                                                                        \
  } while (0)

  STAGE(0, 0);
  __syncthreads();
  int cur = 0;

  for (int t = 0; t < nsteps; ++t) {
    if (t + 1 < nsteps) STAGE(cur ^ 1, t + 1);

    // ---- QK^T swapped: s[qt][kt][r] = S[kv=kt*16+g*4+r][q=qt*16+cq]
    f32x4 s00 = {}, s01 = {}, s10 = {}, s11 = {};
#pragma unroll
    for (int kc = 0; kc < 4; ++kc) {
      bf16x8 kf0 = *(const bf16x8*)&Kt[cur][cq][((kc * 4 + g) ^ cq) * 8];
      bf16x8 kf1 = *(const bf16x8*)&Kt[cur][16 + cq][((kc * 4 + g) ^ cq) * 8];
      s00 = __builtin_amdgcn_mfma_f32_16x16x32_bf16(kf0, qf[0][kc], s00, 0, 0, 0);
      s01 = __builtin_amdgcn_mfma_f32_16x16x32_bf16(kf1, qf[0][kc], s01, 0, 0, 0);
      s10 = __builtin_amdgcn_mfma_f32_16x16x32_bf16(kf0, qf[1][kc], s10, 0, 0, 0);
      s11 = __builtin_amdgcn_mfma_f32_16x16x32_bf16(kf1, qf[1][kc], s11, 0, 0, 0);
    }
    // ---- lane-local max per q-column (reduce over g groups only)
    float mx0 = fmaxf(fmaxf(fmaxf(s00[0], s00[1]), fmaxf(s00[2], s00[3])),
                      fmaxf(fmaxf(s01[0], s01[1]), fmaxf(s01[2], s01[3])));
    float mx1 = fmaxf(fmaxf(fmaxf(s10[0], s10[1]), fmaxf(s10[2], s10[3])),
                      fmaxf(fmaxf(s11[0], s11[1]), fmaxf(s11[2], s11[3])));
    mx0 = fmaxf(mx0, __shfl_xor(mx0, 16)); mx0 = fmaxf(mx0, __shfl_xor(mx0, 32));
    mx1 = fmaxf(mx1, __shfl_xor(mx1, 16)); mx1 = fmaxf(mx1, __shfl_xor(mx1, 32));

    // ---- defer-max rescale (THR=8)
    if (__any((mx0 > m[0] + 8.0f) | (mx1 > m[1] + 8.0f))) {
      float al[2];
      const float mn0 = fmaxf(m[0], mx0), mn1 = fmaxf(m[1], mx1);
      al[0] = __expf(m[0] - mn0); m[0] = mn0; l[0] *= al[0];
      al[1] = __expf(m[1] - mn1); m[1] = mn1; l[1] *= al[1];
#pragma unroll
      for (int qt = 0; qt < 2; ++qt) {
        float ar[4];
#pragma unroll
        for (int r = 0; r < 4; ++r) ar[r] = __shfl(al[qt], g * 4 + r);
#pragma unroll
        for (int et = 0; et < 16; ++et) {
          h[qt][et][0] *= ar[0]; h[qt][et][1] *= ar[1];
          h[qt][et][2] *= ar[2]; h[qt][et][3] *= ar[3];
        }
      }
    }
    // ---- exp + row-sum + P pack/write (per-wave LDS tile, no barrier)
#pragma unroll
    for (int qt = 0; qt < 2; ++qt) {
      const f32x4 sa = qt ? s10 : s00;
      const f32x4 sb = qt ? s11 : s01;
      float p0[4], p1[4];
#pragma unroll
      for (int r = 0; r < 4; ++r) { p0[r] = __expf(sa[r] - m[qt]); }
#pragma unroll
      for (int r = 0; r < 4; ++r) { p1[r] = __expf(sb[r] - m[qt]); }
      float rs = (p0[0] + p0[1]) + (p0[2] + p0[3])
               + (p1[0] + p1[1]) + (p1[2] + p1[3]);
      rs += __shfl_xor(rs, 16); rs += __shfl_xor(rs, 32);
      l[qt] += rs;
      bf16x4 w0, w1;
#pragma unroll
      for (int r = 0; r < 4; ++r) { w0[r] = (__bf16)p0[r]; w1[r] = (__bf16)p1[r]; }
      *(bf16x4*)&Pw[w][qt * 16 + cq][g * 4]      = w0;
      *(bf16x4*)&Pw[w][qt * 16 + cq][16 + g * 4] = w1;
    }
    // ---- re-fragment P and run PV
    bf16x8 pa0 = *(const bf16x8*)&Pw[w][cq][g * 8];
    bf16x8 pa1 = *(const bf16x8*)&Pw[w][16 + cq][g * 8];
#pragma unroll
    for (int et = 0; et < 16; ++et) {
      bf16x8 vf = *(const bf16x8*)&Vs[cur][et * 16 + cq][(g ^ ((cq >> 1) & 3)) * 8];
      h[0][et] = __builtin_amdgcn_mfma_f32_16x16x32_bf16(pa0, vf, h[0][et], 0, 0, 0);
      h[1][et] = __builtin_amdgcn_mfma_f32_16x16x32_bf16(pa1, vf, h[1][et], 0, 0, 0);
    }
    __syncthreads();
    cur ^= 1;
  }
#undef STAGE

  if (KSPLIT == 1) {
#pragma unroll
    for (int qt = 0; qt < 2; ++qt) {
      const float inv = 1.0f / l[qt];
      float ir[4];
#pragma unroll
      for (int r = 0; r < 4; ++r) ir[r] = __shfl(inv, g * 4 + r);
#pragma unroll
      for (int et = 0; et < 16; ++et) {
#pragma unroll
        for (int r = 0; r < 4; ++r) {
          const int n = n0 + qt * 16 + g * 4 + r;
          Hout[((size_t)b * NN + n) * NE + et * 16 + cq] =
              (__bf16)(h[qt][et][r] * ir[r]);
        }
      }
    }
  } else {
#pragma unroll
    for (int qt = 0; qt < 2; ++qt) {
#pragma unroll
      for (int et = 0; et < 16; ++et) {
#pragma unroll
        for (int r = 0; r < 4; ++r) {
          const int n = n0 + qt * 16 + g * 4 + r;
          Hout[(((size_t)split * NB + b) * NN + n) * NE + et * 16 + cq] =
              (__bf16)h[qt][et][r];
        }
      }
    }
    if (g == 0) {
#pragma unroll
      for (int qt = 0; qt < 2; ++qt)
        ml[((size_t)split * NB + b) * NN + n0 + qt * 16 + cq] =
            make_float2(m[qt], l[qt]);
    }
  }
}

// --------------------------------------------- out proj (+fused combine) ----
// swapped operands: D[f][n] = Wo . H^T; split-combine done inline per n-col.
template<int KS>
__global__ __launch_bounds__(256) void outproj_k(
    const __bf16* __restrict__ Hp, const float2* __restrict__ ml,
    const __bf16* __restrict__ Wob, const float* __restrict__ bo,
    const float* __restrict__ x, float* __restrict__ out)
{
  const int b    = blockIdx.y;
  const int w    = threadIdx.x >> 6;
  const int lane = threadIdx.x & 63;
  const int cq   = lane & 15, g = lane >> 4;
  const int n0   = blockIdx.x * 64 + w * 16;

  const size_t row = (size_t)b * NN + n0 + cq;
  float w0 = 1.f, w1 = 0.f;
  const __bf16* Hb0 = Hp + row * NE;
  const __bf16* Hb1 = Hb0;
  if (KS == 2) {
    const float2 a = ml[row];
    const float2 c = ml[(size_t)NB * NN + row];
    const float M  = fmaxf(a.x, c.x);
    const float e0 = __expf(a.x - M), e1 = __expf(c.x - M);
    const float inv = 1.0f / (e0 * a.y + e1 * c.y);
    w0 = e0 * inv; w1 = e1 * inv;
    Hb1 = Hp + ((size_t)NB * NN + row) * NE;
  }

  f32x4 acc[16] = {};
#pragma unroll
  for (int kc = 0; kc < 8; ++kc) {
    const int kb = kc * 32 + g * 8;
    bf16x8 h0 = *(const bf16x8*)(Hb0 + kb);
    bf16x8 hf;
    if (KS == 2) {
      bf16x8 h1 = *(const bf16x8*)(Hb1 + kb);
#pragma unroll
      for (int s = 0; s < 8; ++s)
        hf[s] = (__bf16)(w0 * (float)h0[s] + w1 * (float)h1[s]);
    } else {
      hf = h0;
    }
#pragma unroll
    for (int ft = 0; ft < 16; ++ft) {
      bf16x8 wo = *(const bf16x8*)(Wob + (ft * 16 + cq) * CH + kb);
      acc[ft] = __builtin_amdgcn_mfma_f32_16x16x32_bf16(wo, hf, acc[ft], 0, 0, 0);
    }
  }
#pragma unroll
  for (int ft = 0; ft < 16; ++ft) {
#pragma unroll
    for (int r = 0; r < 4; ++r) {
      const int f = ft * 16 + g * 4 + r;
      const size_t idx = ((size_t)b * CH + f) * NN + n0 + cq;
      out[idx] = x[idx] + acc[ft][r] + bo[f];
    }
  }
}

// ----------------------------------------------------------------------------
extern "C" void kernel_launch(void* const* d_in, const int* in_sizes, int n_in,
                              void* d_out, int out_size, void* d_ws, size_t ws_size,
                              hipStream_t stream) {
  const float* x  = (const float*)d_in[0];
  const float* y  = (const float*)d_in[1];
  const float* Wq = (const float*)d_in[2];
  const float* bq = (const float*)d_in[3];
  const float* Wk = (const float*)d_in[4];
  const float* bk = (const float*)d_in[5];
  const float* Wv = (const float*)d_in[6];
  const float* bv = (const float*)d_in[7];
  const float* Wo = (const float*)d_in[8];
  const float* bo = (const float*)d_in[9];
  float* out = (float*)d_out;

  char* ws = (char*)d_ws;
  __bf16* Hp = (__bf16*)(ws);                        // 32 MB partials
  __bf16* Q  = (__bf16*)(ws + ((size_t)32 << 20));   //  8 MB [b][n][128]
  __bf16* K  = (__bf16*)(ws + ((size_t)40 << 20));   //  8 MB [b][n][128]
  __bf16* Vt = (__bf16*)(ws + ((size_t)48 << 20));   // 16 MB [b][e][n]
  __bf16* Wb = (__bf16*)(ws + ((size_t)64 << 20));   // 384 KB bf16 weights
  float2* ml = (float2*)(ws + ((size_t)64 << 20) + 393216);  // 512 KB
  __bf16* Wqb = Wb, *Wkb = Wb + 32768, *Wvb = Wb + 65536, *Wob = Wb + 131072;

  dim3 grid(64, 8), blk(256);
  wprep_k  <<<dim3(192), blk, 0, stream>>>(Wq, Wk, Wv, Wo, Wb);
  projall_k<<<grid, blk, 0, stream>>>(x, y, Wqb, bq, Wkb, bk, Wvb, bv, Q, K, Vt);

  const size_t need = ((size_t)64 << 20) + 393216
                    + (size_t)2 * NB * NN * sizeof(float2);
  if (ws_size >= need) {
    attn4_k<2><<<dim3(32, 8, 2), blk, 0, stream>>>(Q, K, Vt, Hp, ml);
    outproj_k<2><<<grid, blk, 0, stream>>>(Hp, ml, Wob, bo, x, out);
  } else {
    attn4_k<1><<<dim3(32, 8, 1), blk, 0, stream>>>(Q, K, Vt, Hp, nullptr);
    outproj_k<1><<<grid, blk, 0, stream>>>(Hp, nullptr, Wob, bo, x, out);
  }
}